// Round 1
// baseline (824.382 us; speedup 1.0000x reference)
//
#include <hip/hip_runtime.h>
#include <hip/hip_bf16.h>
#include <math.h>

// MoE top-2, E=8, D=1024, F=2048, N=8192 tokens.
// Strategy: router -> compact per-expert slot lists (128-aligned segments) ->
// grouped bf16 MFMA GEMM1(+GELU) -> GEMM2 (+gate scatter via fp32 atomic add).

#define E_ 8
#define D_ 1024
#define F_ 2048
#define N_ 8192
#define MAX_MTILES 136                 // ceil((N*K + E*127)/128)
#define MAX_SLOTS (MAX_MTILES * 128)   // 17408

typedef __attribute__((ext_vector_type(8))) short short8;
typedef __attribute__((ext_vector_type(4))) float f32x4;
typedef unsigned short u16;

__device__ __forceinline__ u16 f2bf(float f) {
  unsigned int u = __float_as_uint(f);
  unsigned int r = (u + 0x7fffu + ((u >> 16) & 1u)) >> 16;  // RNE
  return (u16)r;
}

__device__ __forceinline__ void gload_lds16(const void* g, void* lds) {
  __builtin_amdgcn_global_load_lds(
      (const __attribute__((address_space(1))) unsigned int*)g,
      (__attribute__((address_space(3))) unsigned int*)lds,
      16, 0, 0);
}

// ---------------- router: one wave per token ----------------
__global__ __launch_bounds__(256) void router_kernel(
    const float* __restrict__ x, const float* __restrict__ Wr,
    int* __restrict__ texp, float* __restrict__ tgate, int* __restrict__ counts) {
  const int token = blockIdx.x * 4 + (threadIdx.x >> 6);
  const int lane = threadIdx.x & 63;
  const float4* xr = (const float4*)(x + (size_t)token * D_);
  float acc[E_];
#pragma unroll
  for (int e = 0; e < E_; ++e) acc[e] = 0.f;
#pragma unroll
  for (int it = 0; it < 4; ++it) {
    const int c4 = it * 64 + lane;   // float4 index within row (0..255)
    const float4 xv = xr[c4];
#pragma unroll
    for (int e = 0; e < E_; ++e) {
      const float4 wv = ((const float4*)(Wr + e * D_))[c4];
      acc[e] += xv.x * wv.x + xv.y * wv.y + xv.z * wv.z + xv.w * wv.w;
    }
  }
#pragma unroll
  for (int e = 0; e < E_; ++e)
#pragma unroll
    for (int s = 32; s > 0; s >>= 1) acc[e] += __shfl_xor(acc[e], s, 64);
  if (lane == 0) {
    int e0 = 0;
#pragma unroll
    for (int e = 1; e < E_; ++e) if (acc[e] > acc[e0]) e0 = e;
    int e1 = (e0 == 0) ? 1 : 0;
#pragma unroll
    for (int e = 0; e < E_; ++e) if (e != e0 && acc[e] > acc[e1]) e1 = e;
    // renormalized top-2 softmax gates == 2-way softmax over top-2 logits
    const float g0 = 1.f / (1.f + __expf(acc[e1] - acc[e0]));
    texp[2 * token] = e0; texp[2 * token + 1] = e1;
    tgate[2 * token] = g0; tgate[2 * token + 1] = 1.f - g0;
    atomicAdd(&counts[e0], 1);
    atomicAdd(&counts[e1], 1);
  }
}

__global__ void offsets_kernel(const int* __restrict__ counts,
                               int* __restrict__ off, int* __restrict__ cursors) {
  if (threadIdx.x == 0) {
    int o = 0;
    for (int e = 0; e < E_; ++e) {
      off[e] = o; cursors[e] = o;
      o += (counts[e] + 127) & ~127;   // 128-align each expert segment
    }
    off[E_] = o;
  }
}

__global__ void initslots_kernel(int* __restrict__ tok, float* __restrict__ gate) {
  const int s = blockIdx.x * 256 + threadIdx.x;
  tok[s] = 0;       // pad slots: valid token 0 ...
  gate[s] = 0.f;    // ... with zero gate -> contributes exactly 0
}

__global__ void place_kernel(const int* __restrict__ texp, const float* __restrict__ tgate,
                             int* __restrict__ cursors, int* __restrict__ tok,
                             float* __restrict__ gate) {
  const int n = blockIdx.x * 256 + threadIdx.x;
  if (n >= N_) return;
#pragma unroll
  for (int k = 0; k < 2; ++k) {
    const int e = texp[2 * n + k];
    const int p = atomicAdd(&cursors[e], 1);
    tok[p] = n;
    gate[p] = tgate[2 * n + k];
  }
}

// ---------------- casts ----------------
__global__ __launch_bounds__(256) void cast_x_kernel(const float* __restrict__ x,
                                                     u16* __restrict__ xb) {
  const int i = blockIdx.x * 256 + threadIdx.x;  // per float4
  const float4 v = ((const float4*)x)[i];
  ushort4 o;
  o.x = f2bf(v.x); o.y = f2bf(v.y); o.z = f2bf(v.z); o.w = f2bf(v.w);
  ((ushort4*)xb)[i] = o;
}

// in[e][r][c] (fp32) -> out[e][c][r] (bf16)
__global__ __launch_bounds__(256) void transpose_cast_kernel(
    const float* __restrict__ in, u16* __restrict__ out, int R, int C) {
  __shared__ float tile[32][33];
  const int e = blockIdx.z;
  const int c0 = blockIdx.x * 32, r0 = blockIdx.y * 32;
  const float* src = in + (size_t)e * R * C;
  u16* dst = out + (size_t)e * R * C;
  for (int i = threadIdx.y; i < 32; i += 8)
    tile[i][threadIdx.x] = src[(size_t)(r0 + i) * C + c0 + threadIdx.x];
  __syncthreads();
  for (int i = threadIdx.y; i < 32; i += 8)
    dst[(size_t)(c0 + i) * R + r0 + threadIdx.x] = f2bf(tile[threadIdx.x][i]);
}

// ---------------- grouped GEMMs (m97-style: 128x128 tile, BK=32) ----------------
// GEMM1: h[slot,f] = gelu( sum_d xb[tok[slot],d] * W1t[e][f,d] + b1[e][f] )
__global__ __launch_bounds__(256) void gemm1_kernel(
    const u16* __restrict__ xb, const u16* __restrict__ w1t,
    const float* __restrict__ b1, const int* __restrict__ tok,
    const int* __restrict__ off, u16* __restrict__ h) {
  __shared__ __align__(16) u16 As[128 * 32];
  __shared__ __align__(16) u16 Bs[128 * 32];
  const int base = blockIdx.y * 128;
  if (base >= off[E_]) return;
  int e = 0;
#pragma unroll
  for (int i = 1; i < E_; ++i) if (base >= off[i]) e = i;

  const int t = threadIdx.x;
  const int w = t >> 6, l = t & 63;
  const int arow = t >> 2;           // 0..63
  const int acol = (t & 3) * 8;      // element offset in K-tile
  const int tok0 = tok[base + arow];
  const int tok1 = tok[base + 64 + arow];
  const u16* gA0 = xb + (size_t)tok0 * D_ + acol;
  const u16* gA1 = xb + (size_t)tok1 * D_ + acol;
  const int f0 = blockIdx.x * 128 + arow;
  const u16* gB0 = w1t + ((size_t)e * F_ + f0) * D_ + acol;
  const u16* gB1 = w1t + ((size_t)e * F_ + f0 + 64) * D_ + acol;
  u16* AsW0 = &As[w * 512];
  u16* AsW1 = &As[64 * 32 + w * 512];
  u16* BsW0 = &Bs[w * 512];
  u16* BsW1 = &Bs[64 * 32 + w * 512];

  const int wm = w >> 1, wn = w & 1;
  const int lc = l & 15, lg = l >> 4;

  f32x4 acc[4][4];
#pragma unroll
  for (int i = 0; i < 4; ++i)
#pragma unroll
    for (int j = 0; j < 4; ++j) acc[i][j] = (f32x4)(0.f);

  for (int kt = 0; kt < D_ / 32; ++kt) {
    const int k0 = kt * 32;
    gload_lds16(gA0 + k0, AsW0);
    gload_lds16(gA1 + k0, AsW1);
    gload_lds16(gB0 + k0, BsW0);
    gload_lds16(gB1 + k0, BsW1);
    __syncthreads();
    short8 a[4], b[4];
#pragma unroll
    for (int mi = 0; mi < 4; ++mi)
      a[mi] = *(const short8*)&As[(wm * 64 + mi * 16 + lc) * 32 + lg * 8];
#pragma unroll
    for (int ni = 0; ni < 4; ++ni)
      b[ni] = *(const short8*)&Bs[(wn * 64 + ni * 16 + lc) * 32 + lg * 8];
#pragma unroll
    for (int mi = 0; mi < 4; ++mi)
#pragma unroll
      for (int ni = 0; ni < 4; ++ni)
        acc[mi][ni] = __builtin_amdgcn_mfma_f32_16x16x32_bf16(a[mi], b[ni], acc[mi][ni], 0, 0, 0);
    __syncthreads();
  }
#pragma unroll
  for (int ni = 0; ni < 4; ++ni) {
    const int gcol = blockIdx.x * 128 + wn * 64 + ni * 16 + lc;
    const float bias = b1[e * F_ + gcol];
#pragma unroll
    for (int mi = 0; mi < 4; ++mi)
#pragma unroll
      for (int r = 0; r < 4; ++r) {
        const int slot = base + wm * 64 + mi * 16 + lg * 4 + r;
        const float v = acc[mi][ni][r] + bias;
        const float g = 0.5f * v * (1.f + erff(v * 0.70710678118654752f));
        h[(size_t)slot * F_ + gcol] = f2bf(g);
      }
  }
}

// GEMM2: out[tok[slot],d] += gate[slot] * ( sum_f h[slot,f]*W2t[e][d,f] + b2[e][d] )
__global__ __launch_bounds__(256) void gemm2_kernel(
    const u16* __restrict__ h, const u16* __restrict__ w2t,
    const float* __restrict__ b2, const int* __restrict__ tok,
    const float* __restrict__ gate, const int* __restrict__ off,
    float* __restrict__ out) {
  __shared__ __align__(16) u16 As[128 * 32];
  __shared__ __align__(16) u16 Bs[128 * 32];
  const int base = blockIdx.y * 128;
  if (base >= off[E_]) return;
  int e = 0;
#pragma unroll
  for (int i = 1; i < E_; ++i) if (base >= off[i]) e = i;

  const int t = threadIdx.x;
  const int w = t >> 6, l = t & 63;
  const int arow = t >> 2;
  const int acol = (t & 3) * 8;
  const u16* gA0 = h + (size_t)(base + arow) * F_ + acol;
  const u16* gA1 = h + (size_t)(base + 64 + arow) * F_ + acol;
  const int d0 = blockIdx.x * 128 + arow;
  const u16* gB0 = w2t + ((size_t)e * D_ + d0) * F_ + acol;
  const u16* gB1 = w2t + ((size_t)e * D_ + d0 + 64) * F_ + acol;
  u16* AsW0 = &As[w * 512];
  u16* AsW1 = &As[64 * 32 + w * 512];
  u16* BsW0 = &Bs[w * 512];
  u16* BsW1 = &Bs[64 * 32 + w * 512];

  const int wm = w >> 1, wn = w & 1;
  const int lc = l & 15, lg = l >> 4;

  f32x4 acc[4][4];
#pragma unroll
  for (int i = 0; i < 4; ++i)
#pragma unroll
    for (int j = 0; j < 4; ++j) acc[i][j] = (f32x4)(0.f);

  for (int kt = 0; kt < F_ / 32; ++kt) {
    const int k0 = kt * 32;
    gload_lds16(gA0 + k0, AsW0);
    gload_lds16(gA1 + k0, AsW1);
    gload_lds16(gB0 + k0, BsW0);
    gload_lds16(gB1 + k0, BsW1);
    __syncthreads();
    short8 a[4], b[4];
#pragma unroll
    for (int mi = 0; mi < 4; ++mi)
      a[mi] = *(const short8*)&As[(wm * 64 + mi * 16 + lc) * 32 + lg * 8];
#pragma unroll
    for (int ni = 0; ni < 4; ++ni)
      b[ni] = *(const short8*)&Bs[(wn * 64 + ni * 16 + lc) * 32 + lg * 8];
#pragma unroll
    for (int mi = 0; mi < 4; ++mi)
#pragma unroll
      for (int ni = 0; ni < 4; ++ni)
        acc[mi][ni] = __builtin_amdgcn_mfma_f32_16x16x32_bf16(a[mi], b[ni], acc[mi][ni], 0, 0, 0);
    __syncthreads();
  }
#pragma unroll
  for (int ni = 0; ni < 4; ++ni) {
    const int gcol = blockIdx.x * 128 + wn * 64 + ni * 16 + lc;
    const float bias = b2[e * D_ + gcol];
#pragma unroll
    for (int mi = 0; mi < 4; ++mi)
#pragma unroll
      for (int r = 0; r < 4; ++r) {
        const int slot = base + wm * 64 + mi * 16 + lg * 4 + r;
        const float gt = gate[slot];
        const int tk = tok[slot];
        const float v = gt * (acc[mi][ni][r] + bias);
        unsafeAtomicAdd(&out[(size_t)tk * D_ + gcol], v);  // exactly 2 adds/elem + zero pads
      }
  }
}

// ---------------- launch ----------------
extern "C" void kernel_launch(void* const* d_in, const int* in_sizes, int n_in,
                              void* d_out, int out_size, void* d_ws, size_t ws_size,
                              hipStream_t stream) {
  const float* x  = (const float*)d_in[0];
  const float* Wr = (const float*)d_in[1];
  const float* W1 = (const float*)d_in[2];
  const float* b1 = (const float*)d_in[3];
  const float* W2 = (const float*)d_in[4];
  const float* b2 = (const float*)d_in[5];
  float* out = (float*)d_out;

  char* p = (char*)d_ws;
  u16* xb  = (u16*)p;  p += (size_t)N_ * D_ * 2;
  u16* w1t = (u16*)p;  p += (size_t)E_ * D_ * F_ * 2;
  u16* w2t = (u16*)p;  p += (size_t)E_ * D_ * F_ * 2;
  u16* h   = (u16*)p;  p += (size_t)MAX_SLOTS * F_ * 2;
  int*   texp  = (int*)p;   p += (size_t)N_ * 2 * 4;
  float* tgate = (float*)p; p += (size_t)N_ * 2 * 4;
  int*   tok   = (int*)p;   p += (size_t)MAX_SLOTS * 4;
  float* gate  = (float*)p; p += (size_t)MAX_SLOTS * 4;
  int* counts  = (int*)p;   // 8
  int* off     = counts + E_;      // 9
  int* cursors = off + E_ + 1;     // 8

  hipMemsetAsync(counts, 0, (E_ + E_ + 1 + E_) * sizeof(int), stream);
  hipMemsetAsync(out, 0, (size_t)out_size * sizeof(float), stream);

  router_kernel<<<N_ / 4, 256, 0, stream>>>(x, Wr, texp, tgate, counts);
  offsets_kernel<<<1, 64, 0, stream>>>(counts, off, cursors);
  initslots_kernel<<<MAX_SLOTS / 256, 256, 0, stream>>>(tok, gate);
  place_kernel<<<N_ / 256, 256, 0, stream>>>(texp, tgate, cursors, tok, gate);

  cast_x_kernel<<<(N_ * D_ / 4) / 256, 256, 0, stream>>>(x, xb);
  dim3 tb(32, 8);
  transpose_cast_kernel<<<dim3(F_ / 32, D_ / 32, E_), tb, 0, stream>>>(W1, w1t, D_, F_);
  transpose_cast_kernel<<<dim3(D_ / 32, F_ / 32, E_), tb, 0, stream>>>(W2, w2t, F_, D_);

  gemm1_kernel<<<dim3(F_ / 128, MAX_MTILES), 256, 0, stream>>>(xb, w1t, b1, tok, off, h);
  gemm2_kernel<<<dim3(D_ / 128, MAX_MTILES), 256, 0, stream>>>(h, w2t, b2, tok, gate, off, out);
}

// Round 2
// 810.996 us; speedup vs baseline: 1.0165x; 1.0165x over previous
//
#include <hip/hip_runtime.h>
#include <hip/hip_bf16.h>
#include <math.h>

// MoE top-2, E=8, D=1024, F=2048, N=8192 tokens.
// Router -> compact per-expert slot lists (128-aligned segments) ->
// grouped bf16 MFMA GEMM1(+GELU) -> GEMM2 (+gate scatter via fp32 atomic add).
// R1: XCD-aware swizzle — each XCD owns 17 contiguous M-tiles (~one expert's
// weight slab fits its 4MB L2); N-blocks of an M-tile adjacent in dispatch.

#define E_ 8
#define D_ 1024
#define F_ 2048
#define N_ 8192
#define MAX_MTILES 136                 // ceil((N*K + E*127)/128)
#define MAX_SLOTS (MAX_MTILES * 128)   // 17408

typedef __attribute__((ext_vector_type(8))) short short8;
typedef __attribute__((ext_vector_type(4))) float f32x4;
typedef unsigned short u16;

__device__ __forceinline__ u16 f2bf(float f) {
  unsigned int u = __float_as_uint(f);
  unsigned int r = (u + 0x7fffu + ((u >> 16) & 1u)) >> 16;  // RNE
  return (u16)r;
}

__device__ __forceinline__ void gload_lds16(const void* g, void* lds) {
  __builtin_amdgcn_global_load_lds(
      (const __attribute__((address_space(1))) unsigned int*)g,
      (__attribute__((address_space(3))) unsigned int*)lds,
      16, 0, 0);
}

// ---------------- router: one wave per token ----------------
__global__ __launch_bounds__(256) void router_kernel(
    const float* __restrict__ x, const float* __restrict__ Wr,
    int* __restrict__ texp, float* __restrict__ tgate, int* __restrict__ counts) {
  const int token = blockIdx.x * 4 + (threadIdx.x >> 6);
  const int lane = threadIdx.x & 63;
  const float4* xr = (const float4*)(x + (size_t)token * D_);
  float acc[E_];
#pragma unroll
  for (int e = 0; e < E_; ++e) acc[e] = 0.f;
#pragma unroll
  for (int it = 0; it < 4; ++it) {
    const int c4 = it * 64 + lane;   // float4 index within row (0..255)
    const float4 xv = xr[c4];
#pragma unroll
    for (int e = 0; e < E_; ++e) {
      const float4 wv = ((const float4*)(Wr + e * D_))[c4];
      acc[e] += xv.x * wv.x + xv.y * wv.y + xv.z * wv.z + xv.w * wv.w;
    }
  }
#pragma unroll
  for (int e = 0; e < E_; ++e)
#pragma unroll
    for (int s = 32; s > 0; s >>= 1) acc[e] += __shfl_xor(acc[e], s, 64);
  if (lane == 0) {
    int e0 = 0;
#pragma unroll
    for (int e = 1; e < E_; ++e) if (acc[e] > acc[e0]) e0 = e;
    int e1 = (e0 == 0) ? 1 : 0;
#pragma unroll
    for (int e = 0; e < E_; ++e) if (e != e0 && acc[e] > acc[e1]) e1 = e;
    // renormalized top-2 softmax gates == 2-way softmax over top-2 logits
    const float g0 = 1.f / (1.f + __expf(acc[e1] - acc[e0]));
    texp[2 * token] = e0; texp[2 * token + 1] = e1;
    tgate[2 * token] = g0; tgate[2 * token + 1] = 1.f - g0;
    atomicAdd(&counts[e0], 1);
    atomicAdd(&counts[e1], 1);
  }
}

__global__ void offsets_kernel(const int* __restrict__ counts,
                               int* __restrict__ off, int* __restrict__ cursors) {
  if (threadIdx.x == 0) {
    int o = 0;
    for (int e = 0; e < E_; ++e) {
      off[e] = o; cursors[e] = o;
      o += (counts[e] + 127) & ~127;   // 128-align each expert segment
    }
    off[E_] = o;
  }
}

__global__ void initslots_kernel(int* __restrict__ tok, float* __restrict__ gate) {
  const int s = blockIdx.x * 256 + threadIdx.x;
  tok[s] = 0;       // pad slots: valid token 0 ...
  gate[s] = 0.f;    // ... with zero gate -> contributes exactly 0
}

__global__ void place_kernel(const int* __restrict__ texp, const float* __restrict__ tgate,
                             int* __restrict__ cursors, int* __restrict__ tok,
                             float* __restrict__ gate) {
  const int n = blockIdx.x * 256 + threadIdx.x;
  if (n >= N_) return;
#pragma unroll
  for (int k = 0; k < 2; ++k) {
    const int e = texp[2 * n + k];
    const int p = atomicAdd(&cursors[e], 1);
    tok[p] = n;
    gate[p] = tgate[2 * n + k];
  }
}

// ---------------- casts ----------------
__global__ __launch_bounds__(256) void cast_x_kernel(const float* __restrict__ x,
                                                     u16* __restrict__ xb) {
  const int i = blockIdx.x * 256 + threadIdx.x;  // per float4
  const float4 v = ((const float4*)x)[i];
  ushort4 o;
  o.x = f2bf(v.x); o.y = f2bf(v.y); o.z = f2bf(v.z); o.w = f2bf(v.w);
  ((ushort4*)xb)[i] = o;
}

// in[e][r][c] (fp32) -> out[e][c][r] (bf16)
__global__ __launch_bounds__(256) void transpose_cast_kernel(
    const float* __restrict__ in, u16* __restrict__ out, int R, int C) {
  __shared__ float tile[32][33];
  const int e = blockIdx.z;
  const int c0 = blockIdx.x * 32, r0 = blockIdx.y * 32;
  const float* src = in + (size_t)e * R * C;
  u16* dst = out + (size_t)e * R * C;
  for (int i = threadIdx.y; i < 32; i += 8)
    tile[i][threadIdx.x] = src[(size_t)(r0 + i) * C + c0 + threadIdx.x];
  __syncthreads();
  for (int i = threadIdx.y; i < 32; i += 8)
    dst[(size_t)(c0 + i) * R + r0 + threadIdx.x] = f2bf(tile[threadIdx.x][i]);
}

// ---------------- grouped GEMMs (m97-style: 128x128 tile, BK=32) ----------------
// GEMM1: h[slot,f] = gelu( sum_d xb[tok[slot],d] * W1t[e][f,d] + b1[e][f] )
__global__ __launch_bounds__(256) void gemm1_kernel(
    const u16* __restrict__ xb, const u16* __restrict__ w1t,
    const float* __restrict__ b1, const int* __restrict__ tok,
    const int* __restrict__ off, u16* __restrict__ h) {
  __shared__ __align__(16) u16 As[128 * 32];
  __shared__ __align__(16) u16 Bs[128 * 32];
  // XCD-aware swizzle: 2176 blocks; xcd=b&7 owns M-tiles [xcd*17, xcd*17+17);
  // the 16 N-blocks of an M-tile are adjacent in dispatch (co-resident).
  const int b = blockIdx.x;
  const int xcd = b & 7;
  const int local = b >> 3;            // 0..271
  const int tn = local & 15;           // 16 N-tiles (F/128)
  const int tm = xcd * 17 + (local >> 4);
  const int base = tm * 128;
  if (base >= off[E_]) return;
  int e = 0;
#pragma unroll
  for (int i = 1; i < E_; ++i) if (base >= off[i]) e = i;

  const int t = threadIdx.x;
  const int w = t >> 6, l = t & 63;
  const int arow = t >> 2;           // 0..63
  const int acol = (t & 3) * 8;      // element offset in K-tile
  const int tok0 = tok[base + arow];
  const int tok1 = tok[base + 64 + arow];
  const u16* gA0 = xb + (size_t)tok0 * D_ + acol;
  const u16* gA1 = xb + (size_t)tok1 * D_ + acol;
  const int f0 = tn * 128 + arow;
  const u16* gB0 = w1t + ((size_t)e * F_ + f0) * D_ + acol;
  const u16* gB1 = w1t + ((size_t)e * F_ + f0 + 64) * D_ + acol;
  u16* AsW0 = &As[w * 512];
  u16* AsW1 = &As[64 * 32 + w * 512];
  u16* BsW0 = &Bs[w * 512];
  u16* BsW1 = &Bs[64 * 32 + w * 512];

  const int wm = w >> 1, wn = w & 1;
  const int lc = l & 15, lg = l >> 4;

  f32x4 acc[4][4];
#pragma unroll
  for (int i = 0; i < 4; ++i)
#pragma unroll
    for (int j = 0; j < 4; ++j) acc[i][j] = (f32x4)(0.f);

  for (int kt = 0; kt < D_ / 32; ++kt) {
    const int k0 = kt * 32;
    gload_lds16(gA0 + k0, AsW0);
    gload_lds16(gA1 + k0, AsW1);
    gload_lds16(gB0 + k0, BsW0);
    gload_lds16(gB1 + k0, BsW1);
    __syncthreads();
    short8 a[4], bb[4];
#pragma unroll
    for (int mi = 0; mi < 4; ++mi)
      a[mi] = *(const short8*)&As[(wm * 64 + mi * 16 + lc) * 32 + lg * 8];
#pragma unroll
    for (int ni = 0; ni < 4; ++ni)
      bb[ni] = *(const short8*)&Bs[(wn * 64 + ni * 16 + lc) * 32 + lg * 8];
#pragma unroll
    for (int mi = 0; mi < 4; ++mi)
#pragma unroll
      for (int ni = 0; ni < 4; ++ni)
        acc[mi][ni] = __builtin_amdgcn_mfma_f32_16x16x32_bf16(a[mi], bb[ni], acc[mi][ni], 0, 0, 0);
    __syncthreads();
  }
#pragma unroll
  for (int ni = 0; ni < 4; ++ni) {
    const int gcol = tn * 128 + wn * 64 + ni * 16 + lc;
    const float bias = b1[e * F_ + gcol];
#pragma unroll
    for (int mi = 0; mi < 4; ++mi)
#pragma unroll
      for (int r = 0; r < 4; ++r) {
        const int slot = base + wm * 64 + mi * 16 + lg * 4 + r;
        const float v = acc[mi][ni][r] + bias;
        const float g = 0.5f * v * (1.f + erff(v * 0.70710678118654752f));
        h[(size_t)slot * F_ + gcol] = f2bf(g);
      }
  }
}

// GEMM2: out[tok[slot],d] += gate[slot] * ( sum_f h[slot,f]*W2t[e][d,f] + b2[e][d] )
__global__ __launch_bounds__(256) void gemm2_kernel(
    const u16* __restrict__ h, const u16* __restrict__ w2t,
    const float* __restrict__ b2, const int* __restrict__ tok,
    const float* __restrict__ gate, const int* __restrict__ off,
    float* __restrict__ out) {
  __shared__ __align__(16) u16 As[128 * 32];
  __shared__ __align__(16) u16 Bs[128 * 32];
  // XCD-aware swizzle: 1088 blocks; xcd=b&7 owns M-tiles [xcd*17, xcd*17+17);
  // same tm chunk as gemm1 -> h locality across kernels on the same XCD.
  const int b = blockIdx.x;
  const int xcd = b & 7;
  const int local = b >> 3;            // 0..135
  const int tn = local & 7;            // 8 N-tiles (D/128)
  const int tm = xcd * 17 + (local >> 3);
  const int base = tm * 128;
  if (base >= off[E_]) return;
  int e = 0;
#pragma unroll
  for (int i = 1; i < E_; ++i) if (base >= off[i]) e = i;

  const int t = threadIdx.x;
  const int w = t >> 6, l = t & 63;
  const int arow = t >> 2;
  const int acol = (t & 3) * 8;
  const u16* gA0 = h + (size_t)(base + arow) * F_ + acol;
  const u16* gA1 = h + (size_t)(base + 64 + arow) * F_ + acol;
  const int d0 = tn * 128 + arow;
  const u16* gB0 = w2t + ((size_t)e * D_ + d0) * F_ + acol;
  const u16* gB1 = w2t + ((size_t)e * D_ + d0 + 64) * F_ + acol;
  u16* AsW0 = &As[w * 512];
  u16* AsW1 = &As[64 * 32 + w * 512];
  u16* BsW0 = &Bs[w * 512];
  u16* BsW1 = &Bs[64 * 32 + w * 512];

  const int wm = w >> 1, wn = w & 1;
  const int lc = l & 15, lg = l >> 4;

  f32x4 acc[4][4];
#pragma unroll
  for (int i = 0; i < 4; ++i)
#pragma unroll
    for (int j = 0; j < 4; ++j) acc[i][j] = (f32x4)(0.f);

  for (int kt = 0; kt < F_ / 32; ++kt) {
    const int k0 = kt * 32;
    gload_lds16(gA0 + k0, AsW0);
    gload_lds16(gA1 + k0, AsW1);
    gload_lds16(gB0 + k0, BsW0);
    gload_lds16(gB1 + k0, BsW1);
    __syncthreads();
    short8 a[4], bb[4];
#pragma unroll
    for (int mi = 0; mi < 4; ++mi)
      a[mi] = *(const short8*)&As[(wm * 64 + mi * 16 + lc) * 32 + lg * 8];
#pragma unroll
    for (int ni = 0; ni < 4; ++ni)
      bb[ni] = *(const short8*)&Bs[(wn * 64 + ni * 16 + lc) * 32 + lg * 8];
#pragma unroll
    for (int mi = 0; mi < 4; ++mi)
#pragma unroll
      for (int ni = 0; ni < 4; ++ni)
        acc[mi][ni] = __builtin_amdgcn_mfma_f32_16x16x32_bf16(a[mi], bb[ni], acc[mi][ni], 0, 0, 0);
    __syncthreads();
  }
#pragma unroll
  for (int ni = 0; ni < 4; ++ni) {
    const int gcol = tn * 128 + wn * 64 + ni * 16 + lc;
    const float bias = b2[e * D_ + gcol];
#pragma unroll
    for (int mi = 0; mi < 4; ++mi)
#pragma unroll
      for (int r = 0; r < 4; ++r) {
        const int slot = base + wm * 64 + mi * 16 + lg * 4 + r;
        const float gt = gate[slot];
        const int tk = tok[slot];
        const float v = gt * (acc[mi][ni][r] + bias);
        unsafeAtomicAdd(&out[(size_t)tk * D_ + gcol], v);  // exactly 2 adds/elem + zero pads
      }
  }
}

// ---------------- launch ----------------
extern "C" void kernel_launch(void* const* d_in, const int* in_sizes, int n_in,
                              void* d_out, int out_size, void* d_ws, size_t ws_size,
                              hipStream_t stream) {
  const float* x  = (const float*)d_in[0];
  const float* Wr = (const float*)d_in[1];
  const float* W1 = (const float*)d_in[2];
  const float* b1 = (const float*)d_in[3];
  const float* W2 = (const float*)d_in[4];
  const float* b2 = (const float*)d_in[5];
  float* out = (float*)d_out;

  char* p = (char*)d_ws;
  u16* xb  = (u16*)p;  p += (size_t)N_ * D_ * 2;
  u16* w1t = (u16*)p;  p += (size_t)E_ * D_ * F_ * 2;
  u16* w2t = (u16*)p;  p += (size_t)E_ * D_ * F_ * 2;
  u16* h   = (u16*)p;  p += (size_t)MAX_SLOTS * F_ * 2;
  int*   texp  = (int*)p;   p += (size_t)N_ * 2 * 4;
  float* tgate = (float*)p; p += (size_t)N_ * 2 * 4;
  int*   tok   = (int*)p;   p += (size_t)MAX_SLOTS * 4;
  float* gate  = (float*)p; p += (size_t)MAX_SLOTS * 4;
  int* counts  = (int*)p;   // 8
  int* off     = counts + E_;      // 9
  int* cursors = off + E_ + 1;     // 8

  hipMemsetAsync(counts, 0, (E_ + E_ + 1 + E_) * sizeof(int), stream);
  hipMemsetAsync(out, 0, (size_t)out_size * sizeof(float), stream);

  router_kernel<<<N_ / 4, 256, 0, stream>>>(x, Wr, texp, tgate, counts);
  offsets_kernel<<<1, 64, 0, stream>>>(counts, off, cursors);
  initslots_kernel<<<MAX_SLOTS / 256, 256, 0, stream>>>(tok, gate);
  place_kernel<<<N_ / 256, 256, 0, stream>>>(texp, tgate, cursors, tok, gate);

  cast_x_kernel<<<(N_ * D_ / 4) / 256, 256, 0, stream>>>(x, xb);
  dim3 tb(32, 8);
  transpose_cast_kernel<<<dim3(F_ / 32, D_ / 32, E_), tb, 0, stream>>>(W1, w1t, D_, F_);
  transpose_cast_kernel<<<dim3(D_ / 32, F_ / 32, E_), tb, 0, stream>>>(W2, w2t, F_, D_);

  gemm1_kernel<<<dim3(16 * MAX_MTILES), 256, 0, stream>>>(xb, w1t, b1, tok, off, h);
  gemm2_kernel<<<dim3(8 * MAX_MTILES), 256, 0, stream>>>(h, w2t, b2, tok, gate, off, out);
}

// Round 3
// 798.747 us; speedup vs baseline: 1.0321x; 1.0153x over previous
//
#include <hip/hip_runtime.h>
#include <hip/hip_bf16.h>
#include <math.h>

// MoE top-2, E=8, D=1024, F=2048, N=8192 tokens.
// R2: K-loop restructured — double-buffered LDS, prefetch held in flight
// across raw s_barrier with s_waitcnt vmcnt(4) (AITER-style), so each
// barrier no longer drains to vmcnt(0). XCD swizzle retained from R1.

#define E_ 8
#define D_ 1024
#define F_ 2048
#define N_ 8192
#define MAX_MTILES 136                 // ceil((N*K + E*127)/128)
#define MAX_SLOTS (MAX_MTILES * 128)   // 17408

typedef __attribute__((ext_vector_type(8))) short short8;
typedef __attribute__((ext_vector_type(4))) float f32x4;
typedef unsigned short u16;

__device__ __forceinline__ u16 f2bf(float f) {
  unsigned int u = __float_as_uint(f);
  unsigned int r = (u + 0x7fffu + ((u >> 16) & 1u)) >> 16;  // RNE
  return (u16)r;
}

__device__ __forceinline__ void gload_lds16(const void* g, void* lds) {
  __builtin_amdgcn_global_load_lds(
      (const __attribute__((address_space(1))) unsigned int*)g,
      (__attribute__((address_space(3))) unsigned int*)lds,
      16, 0, 0);
}

// Raw barrier / waitcnt: keep prefetch loads in flight across the barrier.
__device__ __forceinline__ void raw_barrier() {
  asm volatile("s_barrier" ::: "memory");
}
__device__ __forceinline__ void wait_vmcnt4() {
  asm volatile("s_waitcnt vmcnt(4)" ::: "memory");
}

// ---------------- router: one wave per token ----------------
__global__ __launch_bounds__(256) void router_kernel(
    const float* __restrict__ x, const float* __restrict__ Wr,
    int* __restrict__ texp, float* __restrict__ tgate, int* __restrict__ counts) {
  const int token = blockIdx.x * 4 + (threadIdx.x >> 6);
  const int lane = threadIdx.x & 63;
  const float4* xr = (const float4*)(x + (size_t)token * D_);
  float acc[E_];
#pragma unroll
  for (int e = 0; e < E_; ++e) acc[e] = 0.f;
#pragma unroll
  for (int it = 0; it < 4; ++it) {
    const int c4 = it * 64 + lane;
    const float4 xv = xr[c4];
#pragma unroll
    for (int e = 0; e < E_; ++e) {
      const float4 wv = ((const float4*)(Wr + e * D_))[c4];
      acc[e] += xv.x * wv.x + xv.y * wv.y + xv.z * wv.z + xv.w * wv.w;
    }
  }
#pragma unroll
  for (int e = 0; e < E_; ++e)
#pragma unroll
    for (int s = 32; s > 0; s >>= 1) acc[e] += __shfl_xor(acc[e], s, 64);
  if (lane == 0) {
    int e0 = 0;
#pragma unroll
    for (int e = 1; e < E_; ++e) if (acc[e] > acc[e0]) e0 = e;
    int e1 = (e0 == 0) ? 1 : 0;
#pragma unroll
    for (int e = 0; e < E_; ++e) if (e != e0 && acc[e] > acc[e1]) e1 = e;
    const float g0 = 1.f / (1.f + __expf(acc[e1] - acc[e0]));
    texp[2 * token] = e0; texp[2 * token + 1] = e1;
    tgate[2 * token] = g0; tgate[2 * token + 1] = 1.f - g0;
    atomicAdd(&counts[e0], 1);
    atomicAdd(&counts[e1], 1);
  }
}

__global__ void offsets_kernel(const int* __restrict__ counts,
                               int* __restrict__ off, int* __restrict__ cursors) {
  if (threadIdx.x == 0) {
    int o = 0;
    for (int e = 0; e < E_; ++e) {
      off[e] = o; cursors[e] = o;
      o += (counts[e] + 127) & ~127;
    }
    off[E_] = o;
  }
}

__global__ void initslots_kernel(int* __restrict__ tok, float* __restrict__ gate) {
  const int s = blockIdx.x * 256 + threadIdx.x;
  tok[s] = 0;
  gate[s] = 0.f;
}

__global__ void place_kernel(const int* __restrict__ texp, const float* __restrict__ tgate,
                             int* __restrict__ cursors, int* __restrict__ tok,
                             float* __restrict__ gate) {
  const int n = blockIdx.x * 256 + threadIdx.x;
  if (n >= N_) return;
#pragma unroll
  for (int k = 0; k < 2; ++k) {
    const int e = texp[2 * n + k];
    const int p = atomicAdd(&cursors[e], 1);
    tok[p] = n;
    gate[p] = tgate[2 * n + k];
  }
}

// ---------------- casts ----------------
__global__ __launch_bounds__(256) void cast_x_kernel(const float* __restrict__ x,
                                                     u16* __restrict__ xb) {
  const int i = blockIdx.x * 256 + threadIdx.x;
  const float4 v = ((const float4*)x)[i];
  ushort4 o;
  o.x = f2bf(v.x); o.y = f2bf(v.y); o.z = f2bf(v.z); o.w = f2bf(v.w);
  ((ushort4*)xb)[i] = o;
}

// in[e][r][c] (fp32) -> out[e][c][r] (bf16); 64x64 tiles, coalesced both sides.
__global__ __launch_bounds__(256) void transpose_cast_kernel(
    const float* __restrict__ in, u16* __restrict__ out, int R, int C) {
  __shared__ float tile[64][65];
  const int e = blockIdx.z;
  const int c0 = blockIdx.x * 64, r0 = blockIdx.y * 64;
  const float* src = in + (size_t)e * R * C;
  u16* dst = out + (size_t)e * R * C;
  const int t = threadIdx.x;
  const int rr = t >> 4;        // 0..15
  const int cc = t & 15;        // 0..15
#pragma unroll
  for (int p = 0; p < 4; ++p) {
    const int r = rr + p * 16;
    const float4 v = *(const float4*)&src[(size_t)(r0 + r) * C + c0 + cc * 4];
    tile[r][cc * 4 + 0] = v.x; tile[r][cc * 4 + 1] = v.y;
    tile[r][cc * 4 + 2] = v.z; tile[r][cc * 4 + 3] = v.w;
  }
  __syncthreads();
#pragma unroll
  for (int p = 0; p < 4; ++p) {
    const int c = rr + p * 16;       // dst row = source col
    const int j = cc * 4;
    ushort4 o;
    o.x = f2bf(tile[j + 0][c]);
    o.y = f2bf(tile[j + 1][c]);
    o.z = f2bf(tile[j + 2][c]);
    o.w = f2bf(tile[j + 3][c]);
    *(ushort4*)&dst[(size_t)(c0 + c) * R + r0 + j] = o;
  }
}

// ---------------- grouped GEMMs: 128x128 tile, BK=32, dbuf + vmcnt(4) ------
// GEMM1: h[slot,f] = gelu( sum_d xb[tok[slot],d] * W1t[e][f,d] + b1[e][f] )
__global__ __launch_bounds__(256) void gemm1_kernel(
    const u16* __restrict__ xb, const u16* __restrict__ w1t,
    const float* __restrict__ b1, const int* __restrict__ tok,
    const int* __restrict__ off, u16* __restrict__ h) {
  __shared__ __align__(16) u16 As[2 * 4096];
  __shared__ __align__(16) u16 Bs[2 * 4096];
  const int b = blockIdx.x;
  const int xcd = b & 7;
  const int local = b >> 3;            // 0..271
  const int tn = local & 15;           // 16 N-tiles (F/128)
  const int tm = xcd * 17 + (local >> 4);
  const int base = tm * 128;
  if (base >= off[E_]) return;
  int e = 0;
#pragma unroll
  for (int i = 1; i < E_; ++i) if (base >= off[i]) e = i;

  const int t = threadIdx.x;
  const int w = t >> 6, l = t & 63;
  const int arow = t >> 2;           // 0..63
  const int acol = (t & 3) * 8;
  const int tok0 = tok[base + arow];
  const int tok1 = tok[base + 64 + arow];
  const u16* gA0 = xb + (size_t)tok0 * D_ + acol;
  const u16* gA1 = xb + (size_t)tok1 * D_ + acol;
  const int f0 = tn * 128 + arow;
  const u16* gB0 = w1t + ((size_t)e * F_ + f0) * D_ + acol;
  const u16* gB1 = w1t + ((size_t)e * F_ + f0 + 64) * D_ + acol;

  const int wm = w >> 1, wn = w & 1;
  const int lc = l & 15, lg = l >> 4;

  f32x4 acc[4][4];
#pragma unroll
  for (int i = 0; i < 4; ++i)
#pragma unroll
    for (int j = 0; j < 4; ++j) acc[i][j] = (f32x4)(0.f);

  // prologue: tile 0 into buffer 0
  {
    u16* a0 = &As[w * 512];
    u16* a1 = &As[2048 + w * 512];
    u16* b0 = &Bs[w * 512];
    u16* b1s = &Bs[2048 + w * 512];
    gload_lds16(gA0, a0);
    gload_lds16(gA1, a1);
    gload_lds16(gB0, b0);
    gload_lds16(gB1, b1s);
  }

  const int KT = D_ / 32;  // 32
  for (int kt = 0; kt < KT; ++kt) {
    const int ktn = (kt + 1 < KT) ? kt + 1 : kt;  // tail: redundant prefetch keeps vmcnt math valid
    const int pb = (kt + 1) & 1;
    const int cb = kt & 1;
    {
      const int k0 = ktn * 32;
      u16* a0 = &As[pb * 4096 + w * 512];
      u16* a1 = &As[pb * 4096 + 2048 + w * 512];
      u16* b0 = &Bs[pb * 4096 + w * 512];
      u16* b1s = &Bs[pb * 4096 + 2048 + w * 512];
      gload_lds16(gA0 + k0, a0);
      gload_lds16(gA1 + k0, a1);
      gload_lds16(gB0 + k0, b0);
      gload_lds16(gB1 + k0, b1s);
    }
    wait_vmcnt4();   // current tile (older 4 loads) landed; prefetch stays in flight
    raw_barrier();
    short8 a[4], bb[4];
#pragma unroll
    for (int mi = 0; mi < 4; ++mi)
      a[mi] = *(const short8*)&As[cb * 4096 + (wm * 64 + mi * 16 + lc) * 32 + lg * 8];
#pragma unroll
    for (int ni = 0; ni < 4; ++ni)
      bb[ni] = *(const short8*)&Bs[cb * 4096 + (wn * 64 + ni * 16 + lc) * 32 + lg * 8];
#pragma unroll
    for (int mi = 0; mi < 4; ++mi)
#pragma unroll
      for (int ni = 0; ni < 4; ++ni)
        acc[mi][ni] = __builtin_amdgcn_mfma_f32_16x16x32_bf16(a[mi], bb[ni], acc[mi][ni], 0, 0, 0);
    raw_barrier();   // all waves done reading buffer cb before it is prefetched into
  }
#pragma unroll
  for (int ni = 0; ni < 4; ++ni) {
    const int gcol = tn * 128 + wn * 64 + ni * 16 + lc;
    const float bias = b1[e * F_ + gcol];
#pragma unroll
    for (int mi = 0; mi < 4; ++mi)
#pragma unroll
      for (int r = 0; r < 4; ++r) {
        const int slot = base + wm * 64 + mi * 16 + lg * 4 + r;
        const float v = acc[mi][ni][r] + bias;
        const float g = 0.5f * v * (1.f + erff(v * 0.70710678118654752f));
        h[(size_t)slot * F_ + gcol] = f2bf(g);
      }
  }
}

// GEMM2: out[tok[slot],d] += gate[slot] * ( sum_f h[slot,f]*W2t[e][d,f] + b2[e][d] )
__global__ __launch_bounds__(256) void gemm2_kernel(
    const u16* __restrict__ h, const u16* __restrict__ w2t,
    const float* __restrict__ b2, const int* __restrict__ tok,
    const float* __restrict__ gate, const int* __restrict__ off,
    float* __restrict__ out) {
  __shared__ __align__(16) u16 As[2 * 4096];
  __shared__ __align__(16) u16 Bs[2 * 4096];
  const int b = blockIdx.x;
  const int xcd = b & 7;
  const int local = b >> 3;            // 0..135
  const int tn = local & 7;            // 8 N-tiles (D/128)
  const int tm = xcd * 17 + (local >> 3);
  const int base = tm * 128;
  if (base >= off[E_]) return;
  int e = 0;
#pragma unroll
  for (int i = 1; i < E_; ++i) if (base >= off[i]) e = i;

  const int t = threadIdx.x;
  const int w = t >> 6, l = t & 63;
  const int arow = t >> 2;
  const int acol = (t & 3) * 8;
  const u16* gA0 = h + (size_t)(base + arow) * F_ + acol;
  const u16* gA1 = h + (size_t)(base + 64 + arow) * F_ + acol;
  const int d0 = tn * 128 + arow;
  const u16* gB0 = w2t + ((size_t)e * D_ + d0) * F_ + acol;
  const u16* gB1 = w2t + ((size_t)e * D_ + d0 + 64) * F_ + acol;

  const int wm = w >> 1, wn = w & 1;
  const int lc = l & 15, lg = l >> 4;

  f32x4 acc[4][4];
#pragma unroll
  for (int i = 0; i < 4; ++i)
#pragma unroll
    for (int j = 0; j < 4; ++j) acc[i][j] = (f32x4)(0.f);

  {
    u16* a0 = &As[w * 512];
    u16* a1 = &As[2048 + w * 512];
    u16* b0 = &Bs[w * 512];
    u16* b1s = &Bs[2048 + w * 512];
    gload_lds16(gA0, a0);
    gload_lds16(gA1, a1);
    gload_lds16(gB0, b0);
    gload_lds16(gB1, b1s);
  }

  const int KT = F_ / 32;  // 64
  for (int kt = 0; kt < KT; ++kt) {
    const int ktn = (kt + 1 < KT) ? kt + 1 : kt;
    const int pb = (kt + 1) & 1;
    const int cb = kt & 1;
    {
      const int k0 = ktn * 32;
      u16* a0 = &As[pb * 4096 + w * 512];
      u16* a1 = &As[pb * 4096 + 2048 + w * 512];
      u16* b0 = &Bs[pb * 4096 + w * 512];
      u16* b1s = &Bs[pb * 4096 + 2048 + w * 512];
      gload_lds16(gA0 + k0, a0);
      gload_lds16(gA1 + k0, a1);
      gload_lds16(gB0 + k0, b0);
      gload_lds16(gB1 + k0, b1s);
    }
    wait_vmcnt4();
    raw_barrier();
    short8 a[4], bb[4];
#pragma unroll
    for (int mi = 0; mi < 4; ++mi)
      a[mi] = *(const short8*)&As[cb * 4096 + (wm * 64 + mi * 16 + lc) * 32 + lg * 8];
#pragma unroll
    for (int ni = 0; ni < 4; ++ni)
      bb[ni] = *(const short8*)&Bs[cb * 4096 + (wn * 64 + ni * 16 + lc) * 32 + lg * 8];
#pragma unroll
    for (int mi = 0; mi < 4; ++mi)
#pragma unroll
      for (int ni = 0; ni < 4; ++ni)
        acc[mi][ni] = __builtin_amdgcn_mfma_f32_16x16x32_bf16(a[mi], bb[ni], acc[mi][ni], 0, 0, 0);
    raw_barrier();
  }
#pragma unroll
  for (int ni = 0; ni < 4; ++ni) {
    const int gcol = tn * 128 + wn * 64 + ni * 16 + lc;
    const float bias = b2[e * D_ + gcol];
#pragma unroll
    for (int mi = 0; mi < 4; ++mi)
#pragma unroll
      for (int r = 0; r < 4; ++r) {
        const int slot = base + wm * 64 + mi * 16 + lg * 4 + r;
        const float gt = gate[slot];
        const int tk = tok[slot];
        const float v = gt * (acc[mi][ni][r] + bias);
        unsafeAtomicAdd(&out[(size_t)tk * D_ + gcol], v);
      }
  }
}

// ---------------- launch ----------------
extern "C" void kernel_launch(void* const* d_in, const int* in_sizes, int n_in,
                              void* d_out, int out_size, void* d_ws, size_t ws_size,
                              hipStream_t stream) {
  const float* x  = (const float*)d_in[0];
  const float* Wr = (const float*)d_in[1];
  const float* W1 = (const float*)d_in[2];
  const float* b1 = (const float*)d_in[3];
  const float* W2 = (const float*)d_in[4];
  const float* b2 = (const float*)d_in[5];
  float* out = (float*)d_out;

  char* p = (char*)d_ws;
  u16* xb  = (u16*)p;  p += (size_t)N_ * D_ * 2;
  u16* w1t = (u16*)p;  p += (size_t)E_ * D_ * F_ * 2;
  u16* w2t = (u16*)p;  p += (size_t)E_ * D_ * F_ * 2;
  u16* h   = (u16*)p;  p += (size_t)MAX_SLOTS * F_ * 2;
  int*   texp  = (int*)p;   p += (size_t)N_ * 2 * 4;
  float* tgate = (float*)p; p += (size_t)N_ * 2 * 4;
  int*   tok   = (int*)p;   p += (size_t)MAX_SLOTS * 4;
  float* gate  = (float*)p; p += (size_t)MAX_SLOTS * 4;
  int* counts  = (int*)p;
  int* off     = counts + E_;
  int* cursors = off + E_ + 1;

  hipMemsetAsync(counts, 0, (E_ + E_ + 1 + E_) * sizeof(int), stream);
  hipMemsetAsync(out, 0, (size_t)out_size * sizeof(float), stream);

  router_kernel<<<N_ / 4, 256, 0, stream>>>(x, Wr, texp, tgate, counts);
  offsets_kernel<<<1, 64, 0, stream>>>(counts, off, cursors);
  initslots_kernel<<<MAX_SLOTS / 256, 256, 0, stream>>>(tok, gate);
  place_kernel<<<N_ / 256, 256, 0, stream>>>(texp, tgate, cursors, tok, gate);

  cast_x_kernel<<<(N_ * D_ / 4) / 256, 256, 0, stream>>>(x, xb);
  transpose_cast_kernel<<<dim3(F_ / 64, D_ / 64, E_), 256, 0, stream>>>(W1, w1t, D_, F_);
  transpose_cast_kernel<<<dim3(D_ / 64, F_ / 64, E_), 256, 0, stream>>>(W2, w2t, F_, D_);

  gemm1_kernel<<<dim3(16 * MAX_MTILES), 256, 0, stream>>>(xb, w1t, b1, tok, off, h);
  gemm2_kernel<<<dim3(8 * MAX_MTILES), 256, 0, stream>>>(h, w2t, b2, tok, gate, off, out);
}

// Round 4
// 794.128 us; speedup vs baseline: 1.0381x; 1.0058x over previous
//
#include <hip/hip_runtime.h>
#include <hip/hip_bf16.h>
#include <math.h>

// MoE top-2, E=8, D=1024, F=2048, N=8192 tokens.
// R3: XOR-swizzled LDS staging layout to kill the 8-way ds_read_b128 bank
// conflict (8.65M conflict-cycles, invariant R0-R2). Swizzle is applied on
// the global-fetch side (global_load_lds dest is lane-contiguous, so the
// layout permutation must come from permuting which chunk each lane loads):
//   lane t stages colgroup (t&3) ^ ((t>>3)&3) of its row;
//   fragment (row r, cg) reads LDS at r*32 + ((cg ^ ((r>>1)&3))*8) u16.

#define E_ 8
#define D_ 1024
#define F_ 2048
#define N_ 8192
#define MAX_MTILES 136                 // ceil((N*K + E*127)/128)
#define MAX_SLOTS (MAX_MTILES * 128)   // 17408

typedef __attribute__((ext_vector_type(8))) short short8;
typedef __attribute__((ext_vector_type(4))) float f32x4;
typedef unsigned short u16;

__device__ __forceinline__ u16 f2bf(float f) {
  unsigned int u = __float_as_uint(f);
  unsigned int r = (u + 0x7fffu + ((u >> 16) & 1u)) >> 16;  // RNE
  return (u16)r;
}

__device__ __forceinline__ void gload_lds16(const void* g, void* lds) {
  __builtin_amdgcn_global_load_lds(
      (const __attribute__((address_space(1))) unsigned int*)g,
      (__attribute__((address_space(3))) unsigned int*)lds,
      16, 0, 0);
}

__device__ __forceinline__ void raw_barrier() {
  asm volatile("s_barrier" ::: "memory");
}
__device__ __forceinline__ void wait_vmcnt4() {
  asm volatile("s_waitcnt vmcnt(4)" ::: "memory");
}

// ---------------- router: one wave per token ----------------
__global__ __launch_bounds__(256) void router_kernel(
    const float* __restrict__ x, const float* __restrict__ Wr,
    int* __restrict__ texp, float* __restrict__ tgate, int* __restrict__ counts) {
  const int token = blockIdx.x * 4 + (threadIdx.x >> 6);
  const int lane = threadIdx.x & 63;
  const float4* xr = (const float4*)(x + (size_t)token * D_);
  float acc[E_];
#pragma unroll
  for (int e = 0; e < E_; ++e) acc[e] = 0.f;
#pragma unroll
  for (int it = 0; it < 4; ++it) {
    const int c4 = it * 64 + lane;
    const float4 xv = xr[c4];
#pragma unroll
    for (int e = 0; e < E_; ++e) {
      const float4 wv = ((const float4*)(Wr + e * D_))[c4];
      acc[e] += xv.x * wv.x + xv.y * wv.y + xv.z * wv.z + xv.w * wv.w;
    }
  }
#pragma unroll
  for (int e = 0; e < E_; ++e)
#pragma unroll
    for (int s = 32; s > 0; s >>= 1) acc[e] += __shfl_xor(acc[e], s, 64);
  if (lane == 0) {
    int e0 = 0;
#pragma unroll
    for (int e = 1; e < E_; ++e) if (acc[e] > acc[e0]) e0 = e;
    int e1 = (e0 == 0) ? 1 : 0;
#pragma unroll
    for (int e = 0; e < E_; ++e) if (e != e0 && acc[e] > acc[e1]) e1 = e;
    const float g0 = 1.f / (1.f + __expf(acc[e1] - acc[e0]));
    texp[2 * token] = e0; texp[2 * token + 1] = e1;
    tgate[2 * token] = g0; tgate[2 * token + 1] = 1.f - g0;
    atomicAdd(&counts[e0], 1);
    atomicAdd(&counts[e1], 1);
  }
}

__global__ void offsets_kernel(const int* __restrict__ counts,
                               int* __restrict__ off, int* __restrict__ cursors) {
  if (threadIdx.x == 0) {
    int o = 0;
    for (int e = 0; e < E_; ++e) {
      off[e] = o; cursors[e] = o;
      o += (counts[e] + 127) & ~127;
    }
    off[E_] = o;
  }
}

__global__ void initslots_kernel(int* __restrict__ tok, float* __restrict__ gate) {
  const int s = blockIdx.x * 256 + threadIdx.x;
  tok[s] = 0;
  gate[s] = 0.f;
}

__global__ void place_kernel(const int* __restrict__ texp, const float* __restrict__ tgate,
                             int* __restrict__ cursors, int* __restrict__ tok,
                             float* __restrict__ gate) {
  const int n = blockIdx.x * 256 + threadIdx.x;
  if (n >= N_) return;
#pragma unroll
  for (int k = 0; k < 2; ++k) {
    const int e = texp[2 * n + k];
    const int p = atomicAdd(&cursors[e], 1);
    tok[p] = n;
    gate[p] = tgate[2 * n + k];
  }
}

// ---------------- casts ----------------
__global__ __launch_bounds__(256) void cast_x_kernel(const float* __restrict__ x,
                                                     u16* __restrict__ xb) {
  const int i = blockIdx.x * 256 + threadIdx.x;
  const float4 v = ((const float4*)x)[i];
  ushort4 o;
  o.x = f2bf(v.x); o.y = f2bf(v.y); o.z = f2bf(v.z); o.w = f2bf(v.w);
  ((ushort4*)xb)[i] = o;
}

// in[e][r][c] (fp32) -> out[e][c][r] (bf16); 64x64 tiles, coalesced both sides.
__global__ __launch_bounds__(256) void transpose_cast_kernel(
    const float* __restrict__ in, u16* __restrict__ out, int R, int C) {
  __shared__ float tile[64][65];
  const int e = blockIdx.z;
  const int c0 = blockIdx.x * 64, r0 = blockIdx.y * 64;
  const float* src = in + (size_t)e * R * C;
  u16* dst = out + (size_t)e * R * C;
  const int t = threadIdx.x;
  const int rr = t >> 4;        // 0..15
  const int cc = t & 15;        // 0..15
#pragma unroll
  for (int p = 0; p < 4; ++p) {
    const int r = rr + p * 16;
    const float4 v = *(const float4*)&src[(size_t)(r0 + r) * C + c0 + cc * 4];
    tile[r][cc * 4 + 0] = v.x; tile[r][cc * 4 + 1] = v.y;
    tile[r][cc * 4 + 2] = v.z; tile[r][cc * 4 + 3] = v.w;
  }
  __syncthreads();
#pragma unroll
  for (int p = 0; p < 4; ++p) {
    const int c = rr + p * 16;       // dst row = source col
    const int j = cc * 4;
    ushort4 o;
    o.x = f2bf(tile[j + 0][c]);
    o.y = f2bf(tile[j + 1][c]);
    o.z = f2bf(tile[j + 2][c]);
    o.w = f2bf(tile[j + 3][c]);
    *(ushort4*)&dst[(size_t)(c0 + c) * R + r0 + j] = o;
  }
}

// ---------------- grouped GEMMs: 128x128 tile, BK=32, dbuf + swizzled LDS --
// GEMM1: h[slot,f] = gelu( sum_d xb[tok[slot],d] * W1t[e][f,d] + b1[e][f] )
__global__ __launch_bounds__(256) void gemm1_kernel(
    const u16* __restrict__ xb, const u16* __restrict__ w1t,
    const float* __restrict__ b1, const int* __restrict__ tok,
    const int* __restrict__ off, u16* __restrict__ h) {
  __shared__ __align__(16) u16 As[2 * 4096];
  __shared__ __align__(16) u16 Bs[2 * 4096];
  const int b = blockIdx.x;
  const int xcd = b & 7;
  const int local = b >> 3;            // 0..271
  const int tn = local & 15;           // 16 N-tiles (F/128)
  const int tm = xcd * 17 + (local >> 4);
  const int base = tm * 128;
  if (base >= off[E_]) return;
  int e = 0;
#pragma unroll
  for (int i = 1; i < E_; ++i) if (base >= off[i]) e = i;

  const int t = threadIdx.x;
  const int w = t >> 6, l = t & 63;
  const int arow = t >> 2;                         // 0..63
  const int acol = (((t & 3) ^ ((t >> 3) & 3)) * 8);  // swizzled colgroup
  const int tok0 = tok[base + arow];
  const int tok1 = tok[base + 64 + arow];
  const u16* gA0 = xb + (size_t)tok0 * D_ + acol;
  const u16* gA1 = xb + (size_t)tok1 * D_ + acol;
  const int f0 = tn * 128 + arow;
  const u16* gB0 = w1t + ((size_t)e * F_ + f0) * D_ + acol;
  const u16* gB1 = w1t + ((size_t)e * F_ + f0 + 64) * D_ + acol;

  const int wm = w >> 1, wn = w & 1;
  const int lc = l & 15, lg = l >> 4;
  const int swz = (lc >> 1) & 3;            // = ((row>>1)&3) for row = ..+lc
  const int kofs = ((lg ^ swz) * 8);        // swizzled K-chunk within row

  f32x4 acc[4][4];
#pragma unroll
  for (int i = 0; i < 4; ++i)
#pragma unroll
    for (int j = 0; j < 4; ++j) acc[i][j] = (f32x4)(0.f);

  {
    gload_lds16(gA0, &As[w * 512]);
    gload_lds16(gA1, &As[2048 + w * 512]);
    gload_lds16(gB0, &Bs[w * 512]);
    gload_lds16(gB1, &Bs[2048 + w * 512]);
  }

  const int KT = D_ / 32;  // 32
  for (int kt = 0; kt < KT; ++kt) {
    const int ktn = (kt + 1 < KT) ? kt + 1 : kt;  // tail: redundant prefetch keeps vmcnt math valid
    const int pb = (kt + 1) & 1;
    const int cb = kt & 1;
    {
      const int k0 = ktn * 32;
      gload_lds16(gA0 + k0, &As[pb * 4096 + w * 512]);
      gload_lds16(gA1 + k0, &As[pb * 4096 + 2048 + w * 512]);
      gload_lds16(gB0 + k0, &Bs[pb * 4096 + w * 512]);
      gload_lds16(gB1 + k0, &Bs[pb * 4096 + 2048 + w * 512]);
    }
    wait_vmcnt4();   // current tile landed; prefetch stays in flight
    raw_barrier();
    short8 a[4], bb[4];
#pragma unroll
    for (int mi = 0; mi < 4; ++mi)
      a[mi] = *(const short8*)&As[cb * 4096 + (wm * 64 + mi * 16 + lc) * 32 + kofs];
#pragma unroll
    for (int ni = 0; ni < 4; ++ni)
      bb[ni] = *(const short8*)&Bs[cb * 4096 + (wn * 64 + ni * 16 + lc) * 32 + kofs];
#pragma unroll
    for (int mi = 0; mi < 4; ++mi)
#pragma unroll
      for (int ni = 0; ni < 4; ++ni)
        acc[mi][ni] = __builtin_amdgcn_mfma_f32_16x16x32_bf16(a[mi], bb[ni], acc[mi][ni], 0, 0, 0);
    raw_barrier();
  }
#pragma unroll
  for (int ni = 0; ni < 4; ++ni) {
    const int gcol = tn * 128 + wn * 64 + ni * 16 + lc;
    const float bias = b1[e * F_ + gcol];
#pragma unroll
    for (int mi = 0; mi < 4; ++mi)
#pragma unroll
      for (int r = 0; r < 4; ++r) {
        const int slot = base + wm * 64 + mi * 16 + lg * 4 + r;
        const float v = acc[mi][ni][r] + bias;
        const float g = 0.5f * v * (1.f + erff(v * 0.70710678118654752f));
        h[(size_t)slot * F_ + gcol] = f2bf(g);
      }
  }
}

// GEMM2: out[tok[slot],d] += gate[slot] * ( sum_f h[slot,f]*W2t[e][d,f] + b2[e][d] )
__global__ __launch_bounds__(256) void gemm2_kernel(
    const u16* __restrict__ h, const u16* __restrict__ w2t,
    const float* __restrict__ b2, const int* __restrict__ tok,
    const float* __restrict__ gate, const int* __restrict__ off,
    float* __restrict__ out) {
  __shared__ __align__(16) u16 As[2 * 4096];
  __shared__ __align__(16) u16 Bs[2 * 4096];
  const int b = blockIdx.x;
  const int xcd = b & 7;
  const int local = b >> 3;            // 0..135
  const int tn = local & 7;            // 8 N-tiles (D/128)
  const int tm = xcd * 17 + (local >> 3);
  const int base = tm * 128;
  if (base >= off[E_]) return;
  int e = 0;
#pragma unroll
  for (int i = 1; i < E_; ++i) if (base >= off[i]) e = i;

  const int t = threadIdx.x;
  const int w = t >> 6, l = t & 63;
  const int arow = t >> 2;
  const int acol = (((t & 3) ^ ((t >> 3) & 3)) * 8);  // swizzled colgroup
  const u16* gA0 = h + (size_t)(base + arow) * F_ + acol;
  const u16* gA1 = h + (size_t)(base + 64 + arow) * F_ + acol;
  const int d0 = tn * 128 + arow;
  const u16* gB0 = w2t + ((size_t)e * D_ + d0) * F_ + acol;
  const u16* gB1 = w2t + ((size_t)e * D_ + d0 + 64) * F_ + acol;

  const int wm = w >> 1, wn = w & 1;
  const int lc = l & 15, lg = l >> 4;
  const int swz = (lc >> 1) & 3;
  const int kofs = ((lg ^ swz) * 8);

  f32x4 acc[4][4];
#pragma unroll
  for (int i = 0; i < 4; ++i)
#pragma unroll
    for (int j = 0; j < 4; ++j) acc[i][j] = (f32x4)(0.f);

  {
    gload_lds16(gA0, &As[w * 512]);
    gload_lds16(gA1, &As[2048 + w * 512]);
    gload_lds16(gB0, &Bs[w * 512]);
    gload_lds16(gB1, &Bs[2048 + w * 512]);
  }

  const int KT = F_ / 32;  // 64
  for (int kt = 0; kt < KT; ++kt) {
    const int ktn = (kt + 1 < KT) ? kt + 1 : kt;
    const int pb = (kt + 1) & 1;
    const int cb = kt & 1;
    {
      const int k0 = ktn * 32;
      gload_lds16(gA0 + k0, &As[pb * 4096 + w * 512]);
      gload_lds16(gA1 + k0, &As[pb * 4096 + 2048 + w * 512]);
      gload_lds16(gB0 + k0, &Bs[pb * 4096 + w * 512]);
      gload_lds16(gB1 + k0, &Bs[pb * 4096 + 2048 + w * 512]);
    }
    wait_vmcnt4();
    raw_barrier();
    short8 a[4], bb[4];
#pragma unroll
    for (int mi = 0; mi < 4; ++mi)
      a[mi] = *(const short8*)&As[cb * 4096 + (wm * 64 + mi * 16 + lc) * 32 + kofs];
#pragma unroll
    for (int ni = 0; ni < 4; ++ni)
      bb[ni] = *(const short8*)&Bs[cb * 4096 + (wn * 64 + ni * 16 + lc) * 32 + kofs];
#pragma unroll
    for (int mi = 0; mi < 4; ++mi)
#pragma unroll
      for (int ni = 0; ni < 4; ++ni)
        acc[mi][ni] = __builtin_amdgcn_mfma_f32_16x16x32_bf16(a[mi], bb[ni], acc[mi][ni], 0, 0, 0);
    raw_barrier();
  }
#pragma unroll
  for (int ni = 0; ni < 4; ++ni) {
    const int gcol = tn * 128 + wn * 64 + ni * 16 + lc;
    const float bias = b2[e * D_ + gcol];
#pragma unroll
    for (int mi = 0; mi < 4; ++mi)
#pragma unroll
      for (int r = 0; r < 4; ++r) {
        const int slot = base + wm * 64 + mi * 16 + lg * 4 + r;
        const float gt = gate[slot];
        const int tk = tok[slot];
        const float v = gt * (acc[mi][ni][r] + bias);
        unsafeAtomicAdd(&out[(size_t)tk * D_ + gcol], v);
      }
  }
}

// ---------------- launch ----------------
extern "C" void kernel_launch(void* const* d_in, const int* in_sizes, int n_in,
                              void* d_out, int out_size, void* d_ws, size_t ws_size,
                              hipStream_t stream) {
  const float* x  = (const float*)d_in[0];
  const float* Wr = (const float*)d_in[1];
  const float* W1 = (const float*)d_in[2];
  const float* b1 = (const float*)d_in[3];
  const float* W2 = (const float*)d_in[4];
  const float* b2 = (const float*)d_in[5];
  float* out = (float*)d_out;

  char* p = (char*)d_ws;
  u16* xb  = (u16*)p;  p += (size_t)N_ * D_ * 2;
  u16* w1t = (u16*)p;  p += (size_t)E_ * D_ * F_ * 2;
  u16* w2t = (u16*)p;  p += (size_t)E_ * D_ * F_ * 2;
  u16* h   = (u16*)p;  p += (size_t)MAX_SLOTS * F_ * 2;
  int*   texp  = (int*)p;   p += (size_t)N_ * 2 * 4;
  float* tgate = (float*)p; p += (size_t)N_ * 2 * 4;
  int*   tok   = (int*)p;   p += (size_t)MAX_SLOTS * 4;
  float* gate  = (float*)p; p += (size_t)MAX_SLOTS * 4;
  int* counts  = (int*)p;
  int* off     = counts + E_;
  int* cursors = off + E_ + 1;

  hipMemsetAsync(counts, 0, (E_ + E_ + 1 + E_) * sizeof(int), stream);
  hipMemsetAsync(out, 0, (size_t)out_size * sizeof(float), stream);

  router_kernel<<<N_ / 4, 256, 0, stream>>>(x, Wr, texp, tgate, counts);
  offsets_kernel<<<1, 64, 0, stream>>>(counts, off, cursors);
  initslots_kernel<<<MAX_SLOTS / 256, 256, 0, stream>>>(tok, gate);
  place_kernel<<<N_ / 256, 256, 0, stream>>>(texp, tgate, cursors, tok, gate);

  cast_x_kernel<<<(N_ * D_ / 4) / 256, 256, 0, stream>>>(x, xb);
  transpose_cast_kernel<<<dim3(F_ / 64, D_ / 64, E_), 256, 0, stream>>>(W1, w1t, D_, F_);
  transpose_cast_kernel<<<dim3(D_ / 64, F_ / 64, E_), 256, 0, stream>>>(W2, w2t, F_, D_);

  gemm1_kernel<<<dim3(16 * MAX_MTILES), 256, 0, stream>>>(xb, w1t, b1, tok, off, h);
  gemm2_kernel<<<dim3(8 * MAX_MTILES), 256, 0, stream>>>(h, w2t, b2, tok, gate, off, out);
}